// Round 10
// baseline (603.353 us; speedup 1.0000x reference)
//
#include <hip/hip_runtime.h>
#include <stdint.h>

#define B_ 8
#define N_ 1374
#define C_ 768
#define H_ 12
#define HD_ 64
#define HID_ 3072
#define M_ (B_*N_)        // 10992
#define MPAD_ 11008       // 86 * 128 = 172 * 64 = 43 * 256
#define QT_ 22            // ceil(N/64)  (j tiles)
#define QT2_ 11           // ceil(N/128) (q tiles)

// q pre-scale: exp(s/8) == exp2(s * log2(e)/8); fold log2(e)/8 into q at QKV epilogue
#define QSC_ 0.18033688011112042f

typedef __attribute__((ext_vector_type(8))) short short8;
typedef __attribute__((ext_vector_type(4))) float f32x4;
typedef __attribute__((ext_vector_type(16))) float f32x16;
typedef __attribute__((ext_vector_type(4))) _Float16 half4;
typedef __attribute__((ext_vector_type(2))) _Float16 half2v;

__device__ __forceinline__ unsigned short f2bf(float f) {
  unsigned u = __float_as_uint(f);
  u += 0x7FFF + ((u >> 16) & 1);
  return (unsigned short)(u >> 16);
}
__device__ __forceinline__ float bf2f(unsigned short h) {
  return __uint_as_float(((unsigned)h) << 16);
}
__device__ __forceinline__ unsigned short f2h(float f) {
  return __builtin_bit_cast(unsigned short, (_Float16)f);
}

__device__ __forceinline__ half2v pkrtz(float a, float b) {
  return __builtin_bit_cast(half2v, __builtin_amdgcn_cvt_pkrtz(a, b));
}

#if __has_builtin(__builtin_amdgcn_global_load_lds)
#define HAVE_GLL 1
#endif

__device__ __forceinline__ void gld16(const unsigned short* g, unsigned short* l) {
#ifdef HAVE_GLL
  __builtin_amdgcn_global_load_lds((const __attribute__((address_space(1))) void*)g,
                                   (__attribute__((address_space(3))) void*)l, 16, 0, 0);
#else
  *(short8*)l = *(const short8*)g;
#endif
}

// ---------------- LayerNorm body (f32 in, bf16 out), one row per block ----------------
__device__ __forceinline__ void ln_body(const float* __restrict__ in,
    const float* __restrict__ g, const float* __restrict__ bta,
    unsigned short* __restrict__ out, int row, int t) {
  const float* xr = in + (size_t)row * C_;
  float v0 = xr[t], v1 = xr[t + 256], v2 = xr[t + 512];
  float s1 = v0 + v1 + v2;
  float s2 = v0*v0 + v1*v1 + v2*v2;
  for (int off = 1; off < 64; off <<= 1) {
    s1 += __shfl_xor(s1, off, 64);
    s2 += __shfl_xor(s2, off, 64);
  }
  __shared__ float r1[4], r2[4];
  int wave = t >> 6, lane = t & 63;
  if (lane == 0) { r1[wave] = s1; r2[wave] = s2; }
  __syncthreads();
  float tot1 = r1[0] + r1[1] + r1[2] + r1[3];
  float tot2 = r2[0] + r2[1] + r2[2] + r2[3];
  float mu = tot1 * (1.0f / C_);
  float var = tot2 * (1.0f / C_) - mu * mu;
  float rs = rsqrtf(var + 1e-5f);
  size_t ob = (size_t)row * C_;
  out[ob + t]       = f2bf((v0 - mu) * rs * g[t]       + bta[t]);
  out[ob + t + 256] = f2bf((v1 - mu) * rs * g[t + 256] + bta[t + 256]);
  out[ob + t + 512] = f2bf((v2 - mu) * rs * g[t + 512] + bta[t + 512]);
}

__global__ __launch_bounds__(256) void ln_kernel(const float* __restrict__ in,
    const float* __restrict__ g, const float* __restrict__ bta,
    unsigned short* __restrict__ out) {
  ln_body(in, g, bta, out, blockIdx.x, threadIdx.x);
}

// ---------------- fused: weight cvt (blocks 0..9215) + ln1 (blocks 9216..) ----------------
// w1/w2 destinations are remapped into an INTERLEAVED layout Wint[6144][768]:
//   Wint rows [256k, 256k+128) = W1 rows [128k, 128k+128)
//   Wint rows [256k+128, 256k+256) = W2 rows [128k, 128k+128)
// so the 256x256-tile w12 GEMM gets matching x1/x2 columns in one tile.
__global__ __launch_bounds__(256) void cvt5_ln_kernel(
    const float* __restrict__ s0, const float* __restrict__ s1,
    const float* __restrict__ s2, const float* __restrict__ s3,
    const float* __restrict__ s4, unsigned short* __restrict__ out,
    const float* __restrict__ x, const float* __restrict__ ln_g,
    const float* __restrict__ ln_b, unsigned short* __restrict__ h) {
  int blk = blockIdx.x;
  if (blk < 9216) {
    int id = blk * 256 + threadIdx.x;   // float4 index, covers exactly 2359296
    const float* src; int off; int dest = id;
    if (id < 442368)        { src = s0; off = id; }
    else if (id < 589824)   { src = s1; off = id - 442368; }
    else if (id < 1179648)  {           // w1 -> interleaved
      src = s2; off = id - 589824;
      int r = off / 192, c = off % 192;
      int rho = ((r >> 7) << 8) + (r & 127);
      dest = 589824 + rho * 192 + c;
    }
    else if (id < 1769472)  {           // w2 -> interleaved
      src = s3; off = id - 1179648;
      int r = off / 192, c = off % 192;
      int rho = ((r >> 7) << 8) + 128 + (r & 127);
      dest = 589824 + rho * 192 + c;
    }
    else                    { src = s4; off = id - 1769472; }
    float4 v = ((const float4*)src)[off];
    ushort4 o;
    o.x = f2bf(v.x); o.y = f2bf(v.y); o.z = f2bf(v.z); o.w = f2bf(v.w);
    ((ushort4*)out)[dest] = o;
  } else {
    ln_body(x, ln_g, ln_b, h, blk - 9216, threadIdx.x);
  }
}

// ---------------- GEMM: out[M,N] = A[M,K](bf16) * W[N,K]^T(bf16) + epilogue ----------------
// Round-4 proven structure: BK=64 via two stride-32 half-K buffers, 2 barriers
// per K-step.  SWZ supergroup swizzle.
// EPI 0: bf16 out + bias0 (+ fused RoPE on q,k windows; q pre-scaled by QSC_;
//        v window written as f16 for the attention PV mfma)
// EPI 1: f32 out = resid + v + bias, row-guarded
// EPI 3: f32 out += v + bias, row-guarded
template<int EPI, int ROPE, int TM, int SWZ>
__global__ __launch_bounds__(256, (TM == 64) ? 4 : 2) void gemm_bt(
    const unsigned short* __restrict__ A,
    const unsigned short* __restrict__ W,
    void* __restrict__ outp,
    const float* __restrict__ bias0,
    const float* __restrict__ resid,
    const float* __restrict__ freqs,
    int K, int ldo, int Mvalid, int X)
{
  constexpr int MI = TM / 32;   // m-subtiles per wave
  __shared__ __align__(16) unsigned short As[2][TM * 32];
  __shared__ __align__(16) unsigned short Bs[2][4096];
  const int t = threadIdx.x;
  const int lane = t & 63;
  const int wave = t >> 6;
  const int wm = (wave >> 1) * (TM / 2);
  const int wn = (wave & 1) * 64;
  const int lr = lane & 15;
  const int lg = lane >> 4;
  const int lk = lg * 8;
  int bx, by;
  if (SWZ) {
    int Y = gridDim.x / X;
    int lin = blockIdx.x;
    int sgsz = X * 8;
    int sg = lin / sgsz;
    int base_y = sg * 8;
    int rows = Y - base_y; if (rows > 8) rows = 8;
    int within = lin - sg * sgsz;
    by = base_y + within % rows;
    bx = within / rows;
  } else {
    bx = blockIdx.x % X;
    by = blockIdx.x / X;
  }
  const int tm0 = by * TM;
  const int tn0 = bx * 128;
  const int r0 = t >> 2;
  const int c0 = (t & 3) * 8;
  const unsigned short* ga0 = A + (size_t)(tm0 + r0) * K + c0;
  const unsigned short* ga1 = A + (size_t)(tm0 + 64 + r0) * K + c0;   // TM==128 only
  const unsigned short* gb0 = W + (size_t)(tn0 + r0) * K + c0;
  const unsigned short* gb1 = W + (size_t)(tn0 + 64 + r0) * K + c0;
  f32x4 zero = {0.f, 0.f, 0.f, 0.f};
  f32x4 acc[MI][4];
#pragma unroll
  for (int mi = 0; mi < MI; ++mi)
#pragma unroll
    for (int ni = 0; ni < 4; ++ni) acc[mi][ni] = zero;

  for (int kt = 0; kt < K; kt += 64) {
    __syncthreads();
    gld16(ga0 + kt,      &As[0][t * 8]);
    gld16(ga0 + kt + 32, &As[1][t * 8]);
    if (TM == 128) {
      gld16(ga1 + kt,      &As[0][2048 + t * 8]);
      gld16(ga1 + kt + 32, &As[1][2048 + t * 8]);
    }
    gld16(gb0 + kt,      &Bs[0][t * 8]);
    gld16(gb1 + kt,      &Bs[0][2048 + t * 8]);
    gld16(gb0 + kt + 32, &Bs[1][t * 8]);
    gld16(gb1 + kt + 32, &Bs[1][2048 + t * 8]);
    __syncthreads();
#pragma unroll
    for (int u = 0; u < 2; ++u) {
      short8 af[MI], bfr[4];
#pragma unroll
      for (int mi = 0; mi < MI; ++mi) af[mi] = *(const short8*)&As[u][(wm + mi * 16 + lr) * 32 + lk];
#pragma unroll
      for (int ni = 0; ni < 4; ++ni) bfr[ni] = *(const short8*)&Bs[u][(wn + ni * 16 + lr) * 32 + lk];
#pragma unroll
      for (int mi = 0; mi < MI; ++mi)
#pragma unroll
        for (int ni = 0; ni < 4; ++ni)
          acc[mi][ni] = __builtin_amdgcn_mfma_f32_16x16x32_bf16(af[mi], bfr[ni], acc[mi][ni], 0, 0, 0);
    }
  }

  if (EPI == 0) {
    // paired epilogue (cols e and e+32 of a 64-aligned window) for fused RoPE
    bool dorope = ROPE && ((tn0 + wn) < 1536);   // q,k windows only; wave-uniform
    bool isq    = ROPE && ((tn0 + wn) < 768);    // q window: fold attn scale into q
    bool isv    = ROPE && ((tn0 + wn) >= 1536);  // v window: write f16 (PV mfma operand)
#pragma unroll
    for (int mi = 0; mi < MI; ++mi) {
#pragma unroll
      for (int p = 0; p < 2; ++p) {
        int col1 = tn0 + wn + p * 16 + lr;
        int col2 = col1 + 32;
        float bv1 = bias0[col1], bv2 = bias0[col2];
        int e = p * 16 + lr;
#pragma unroll
        for (int r = 0; r < 4; ++r) {
          int row = tm0 + wm + mi * 16 + lg * 4 + r;
          float v1 = acc[mi][p][r] + bv1;
          float v2 = acc[mi][p + 2][r] + bv2;
          float o1 = v1, o2 = v2;
          if (dorope) {
            int n = row % N_;
            float f1 = freqs[n * HD_ + e];
            float f2 = freqs[n * HD_ + e + 32];
            float c1, s1, c2, s2;
            __sincosf(f1, &s1, &c1);
            __sincosf(f2, &s2, &c2);
            o1 = v1 * c1 - v2 * s1;
            o2 = v2 * c2 + v1 * s2;
          }
          if (isq) { o1 *= QSC_; o2 *= QSC_; }
          size_t base = (size_t)row * ldo;
          if (isv) {
            ((unsigned short*)outp)[base + col1] = f2h(o1);
            ((unsigned short*)outp)[base + col2] = f2h(o2);
          } else {
            ((unsigned short*)outp)[base + col1] = f2bf(o1);
            ((unsigned short*)outp)[base + col2] = f2bf(o2);
          }
        }
      }
    }
  } else {
#pragma unroll
    for (int mi = 0; mi < MI; ++mi) {
#pragma unroll
      for (int ni = 0; ni < 4; ++ni) {
        int col = tn0 + wn + ni * 16 + lr;
        float bval = bias0[col];
#pragma unroll
        for (int r = 0; r < 4; ++r) {
          int row = tm0 + wm + mi * 16 + lg * 4 + r;
          float v = acc[mi][ni][r] + bval;
          size_t idx = (size_t)row * ldo + col;
          if (EPI == 1) {
            if (row < Mvalid) ((float*)outp)[idx] = resid[idx] + v;
          } else {
            if (row < Mvalid) ((float*)outp)[idx] = ((float*)outp)[idx] + v;
          }
        }
      }
    }
  }
}

// ---------------- w12: 256x256 8-phase GEMM + swiglu exchange epilogue ----------------
// x12 = A[MPAD,768] * Wint[6144,768]^T, 256x256 output tile, 512 threads (8 waves
// 2Mx4N), BK=64 as two 256x32 k-half planes per operand, double tile-buffered:
// LDS = 2buf x (A:2+B:2 planes) x 16KB = 128KB.
// 8 phases per iteration cover 2 K-tiles; phase (ks,mh): 8 ds_read_b128 +
// stage exactly 1 half-tile (2 gll) + barrier + lgkmcnt(0) + 16 MFMA +
// vmcnt(4) at phases 3/7 only (counted, never 0) + barrier.
// Stage lattice (iter computes tiles T@ph0-3, T+1@ph4-7):
//   ph0: A-khi(T+1)  ph1: B-khi(T+1)  ph2: A-klo(T+2)  ph3: B-klo(T+2)
//   ph4: A-khi(T+2)  ph5: B-khi(T+2)  ph6: A-klo(T+3)  ph7: B-klo(T+3)
// Each plane's write comes >=1 phase after its last read; each tile's loads
// lead its first read by 3-6 phases; vmcnt(4) keeps newest 2 half-tiles in flight.
// Epilogue: x2-waves (wn>=128) park acc in the 128KB LDS (f32 [256][128]),
// x1-waves combine silu(x1+b1)*(x2+b2) and store hid cols [128*bx, +128).
__global__ __launch_bounds__(512, 2) void gemm_w12_8p(
    const unsigned short* __restrict__ A,     // [MPAD,768]
    const unsigned short* __restrict__ Wi,    // [6144,768] interleaved W1/W2
    unsigned short* __restrict__ hid,         // [MPAD,3072]
    const float* __restrict__ b1,
    const float* __restrict__ b2)
{
  __shared__ __align__(16) unsigned short SH[65536];  // 128 KB
  const int t = threadIdx.x;
  const int lane = t & 63;
  const int wave = t >> 6;          // 0..7
  const int wm = (wave >> 2) * 128; // 2 m-groups
  const int wn = (wave & 3) * 64;   // 4 n-groups
  const int lr = lane & 15;
  const int lg = lane >> 4;
  const int bx = blockIdx.x % 24;
  const int by = blockIdx.x / 24;   // x-major: consecutive blocks share A panel
  const int tm0 = by * 256;
  const int tn0 = bx * 256;

  auto plane = [&](int buf, int op, int ks) -> unsigned short* {
    return SH + buf * 32768 + op * 16384 + ks * 8192;   // 256x32 bf16 = 16KB
  };
  auto stageHT = [&](int tile, int op, int ks) {
    if (tile >= 12) return;
    const unsigned short* src = op ? Wi : A;
    int rb = op ? tn0 : tm0;
    unsigned short* pl = plane(tile & 1, op, ks);
    int kc = tile * 64 + ks * 32;
#pragma unroll
    for (int g = 0; g < 2; ++g) {
      int s = g * 512 + t;              // slot 0..1023 (16B each)
      int row = s >> 2;
      int c16 = s & 3;
      gld16(src + (size_t)(rb + row) * 768 + kc + c16 * 8, pl + s * 8);
    }
  };

  f32x4 acc[8][4];
#pragma unroll
  for (int mi = 0; mi < 8; ++mi)
#pragma unroll
    for (int ni = 0; ni < 4; ++ni) acc[mi][ni] = f32x4{0.f, 0.f, 0.f, 0.f};

  // prologue: tile0 all 4 planes, tile1 k-lo planes (12 gll/thread total 6 HTs)
  stageHT(0, 0, 0); stageHT(0, 1, 0); stageHT(0, 0, 1); stageHT(0, 1, 1);
  stageHT(1, 0, 0); stageHT(1, 1, 0);
  asm volatile("s_waitcnt vmcnt(4)" ::: "memory");   // tile0 landed; tile1-klo in flight
  __builtin_amdgcn_s_barrier();

  for (int it = 0; it < 6; ++it) {
    int T = it * 2;
#pragma unroll
    for (int ph = 0; ph < 8; ++ph) {
      const int tile = (ph < 4) ? T : T + 1;
      const int buf = tile & 1;
      const int ks = (ph >> 1) & 1;
      const int mh = ph & 1;
      short8 af[4], bfr[4];
      const unsigned short* Ap = plane(buf, 0, ks);
      const unsigned short* Bp = plane(buf, 1, ks);
#pragma unroll
      for (int i = 0; i < 4; ++i) {
        af[i]  = *(const short8*)&Ap[(wm + (mh * 4 + i) * 16 + lr) * 32 + lg * 8];
        bfr[i] = *(const short8*)&Bp[(wn + i * 16 + lr) * 32 + lg * 8];
      }
      switch (ph) {
        case 0: stageHT(T + 1, 0, 1); break;
        case 1: stageHT(T + 1, 1, 1); break;
        case 2: stageHT(T + 2, 0, 0); break;
        case 3: stageHT(T + 2, 1, 0); break;
        case 4: stageHT(T + 2, 0, 1); break;
        case 5: stageHT(T + 2, 1, 1); break;
        case 6: stageHT(T + 3, 0, 0); break;
        case 7: stageHT(T + 3, 1, 0); break;
      }
      __builtin_amdgcn_s_barrier();
      asm volatile("s_waitcnt lgkmcnt(0)" ::: "memory");
      __builtin_amdgcn_sched_barrier(0);
      __builtin_amdgcn_s_setprio(1);
#pragma unroll
      for (int i = 0; i < 4; ++i)
#pragma unroll
        for (int ni = 0; ni < 4; ++ni)
          acc[mh * 4 + i][ni] = __builtin_amdgcn_mfma_f32_16x16x32_bf16(
              af[i], bfr[ni], acc[mh * 4 + i][ni], 0, 0, 0);
      __builtin_amdgcn_s_setprio(0);
      if (ph == 3 || ph == 7)
        asm volatile("s_waitcnt vmcnt(4)" ::: "memory");
      __builtin_amdgcn_s_barrier();
    }
  }

  // ---- swiglu exchange epilogue ----
  __syncthreads();                       // loop LDS reads all complete; safe to reuse SH
  float* X2 = (float*)SH;                // [256][128] f32 = 128KB
  if ((wave & 3) >= 2) {
    int cb = wn - 128;                   // 0 or 64
#pragma unroll
    for (int mi = 0; mi < 8; ++mi)
#pragma unroll
      for (int ni = 0; ni < 4; ++ni)
#pragma unroll
        for (int r = 0; r < 4; ++r)
          X2[(wm + mi * 16 + lg * 4 + r) * 128 + cb + ni * 16 + lr] = acc[mi][ni][r];
  }
  __syncthreads();
  if ((wave & 3) < 2) {
#pragma unroll
    for (int mi = 0; mi < 8; ++mi) {
#pragma unroll
      for (int ni = 0; ni < 4; ++ni) {
        int cl = wn + ni * 16 + lr;      // 0..127
        float bv1 = b1[bx * 128 + cl];
        float bv2 = b2[bx * 128 + cl];
#pragma unroll
        for (int r = 0; r < 4; ++r) {
          int rl = wm + mi * 16 + lg * 4 + r;
          float a1 = acc[mi][ni][r] + bv1;
          float a2 = X2[rl * 128 + cl] + bv2;
          float h = a1 / (1.f + __expf(-a1)) * a2;
          hid[(size_t)(tm0 + rl) * HID_ + bx * 128 + cl] = f2bf(h);
        }
      }
    }
  }
}

// ---------------- Attention v5: 32x32 MFMA pipeline (verified) ----------------
struct FalseT { static constexpr bool value = false; };
struct TrueT  { static constexpr bool value = true;  };

__global__ __launch_bounds__(256, 3) void attn_kernel(
    const unsigned short* __restrict__ qkv,   // [MPAD_,2304] roped bf16 q,k; f16 v
    unsigned short* __restrict__ o2)          // [MPAD_,768]  bf16
{
  __shared__ __align__(16) unsigned short Ks[2][64 * 88];  // K rows, stride 88
  __shared__ __align__(16) _Float16 Vt[2][64 * 72];        // V^T [d][j], stride 72
  int bidx = blockIdx.x;
  int qt = bidx % QT2_;
  int bh = bidx / QT2_;
  int head = bh % H_;
  int b = bh / H_;
  int t = threadIdx.x, lane = t & 63, wave = t >> 6;
  int lq = lane & 31, lg2 = lane >> 5;

  short8 bq[4];
  {
    int m = qt * 128 + wave * 32 + lq;
    int mc = (m < N_) ? m : (N_ - 1);
    const unsigned short* qrow = qkv + (size_t)(b * N_ + mc) * 2304 + head * HD_;
#pragma unroll
    for (int c = 0; c < 4; ++c)
      bq[c] = *(const short8*)(qrow + c * 16 + lg2 * 8);
  }

  f32x16 acc[2];   // O[q32][d32] per dt
  f32x16 dacc;     // den[q] (ones-MFMA)
  acc[0] = {}; acc[1] = {}; dacc = {};

  const int kr0 = t >> 3;            // K row unit (0..31), also row+32
  const int kc  = (t & 7) * 8;       // K col (element)
  const int vp  = t & 31;            // j-pair 0..31
  const int vc  = t >> 5;            // d-chunk 0..7
  const unsigned short* kbase = qkv + (size_t)(b * N_) * 2304 + 768  + head * HD_ + kc;
  const unsigned short* vbase = qkv + (size_t)(b * N_) * 2304 + 1536 + head * HD_ + vc * 8;

  short8 krg[2], vrg[2];
  auto issue = [&](int jt) {
    int j0 = jt * 64 + kr0;        if (j0 >= N_) j0 = N_ - 1;
    int j1 = jt * 64 + kr0 + 32;   if (j1 >= N_) j1 = N_ - 1;
    int vj0 = jt * 64 + 2 * vp;    if (vj0 >= N_) vj0 = N_ - 1;
    int vj1 = jt * 64 + 2 * vp + 1; if (vj1 >= N_) vj1 = N_ - 1;
    krg[0] = *(const short8*)(kbase + (size_t)j0 * 2304);
    krg[1] = *(const short8*)(kbase + (size_t)j1 * 2304);
    vrg[0] = *(const short8*)(vbase + (size_t)vj0 * 2304);
    vrg[1] = *(const short8*)(vbase + (size_t)vj1 * 2304);
  };

  const half4 vones = {(_Float16)1.f, (_Float16)1.f, (_Float16)1.f, (_Float16)1.f};

  auto compute = [&](int jt, const unsigned short* ksb, const _Float16* vtb, auto tailc) {
    constexpr bool TAIL = decltype(tailc)::value;
#pragma unroll
    for (int st2 = 0; st2 < 2; ++st2) {
      f32x16 sc = {};
      {
        const unsigned short* krow = &ksb[(st2 * 32 + lq) * 88 + lg2 * 8];
        short8 ak0 = *(const short8*)(krow);
        short8 ak1 = *(const short8*)(krow + 16);
        short8 ak2 = *(const short8*)(krow + 32);
        short8 ak3 = *(const short8*)(krow + 48);
        sc = __builtin_amdgcn_mfma_f32_32x32x16_bf16(ak0, bq[0], sc, 0, 0, 0);
        sc = __builtin_amdgcn_mfma_f32_32x32x16_bf16(ak1, bq[1], sc, 0, 0, 0);
        sc = __builtin_amdgcn_mfma_f32_32x32x16_bf16(ak2, bq[2], sc, 0, 0, 0);
        sc = __builtin_amdgcn_mfma_f32_32x32x16_bf16(ak3, bq[3], sc, 0, 0, 0);
      }
#pragma unroll
      for (int r = 0; r < 16; ++r) {
        float pv = exp2f(sc[r]);
        if (TAIL) {
          int jw = (r & 3) + 8 * (r >> 2) + 4 * lg2;
          int j = jt * 64 + st2 * 32 + jw;
          pv = (j < N_) ? pv : 0.f;
        }
        sc[r] = pv;
      }
      half4 pf[4];
#pragma unroll
      for (int ks = 0; ks < 4; ++ks) {
        union { half4 v; half2v h[2]; } pu;
        pu.h[0] = pkrtz(sc[ks * 4 + 0], sc[ks * 4 + 1]);
        pu.h[1] = pkrtz(sc[ks * 4 + 2], sc[ks * 4 + 3]);
        pf[ks] = pu.v;
      }
#pragma unroll
      for (int ks = 0; ks < 4; ++ks)
        dacc = __builtin_amdgcn_mfma_f32_32x32x8f16(pf[ks], vones, dacc, 0, 0, 0);
#pragma unroll
      for (int dt = 0; dt < 2; ++dt) {
#pragma unroll
        for (int ks = 0; ks < 4; ++ks) {
          half4 bv = *(const half4*)&vtb[(dt * 32 + lq) * 72 + st2 * 32 + ks * 8 + lg2 * 4];
          acc[dt] = __builtin_amdgcn_mfma_f32_32x32x8f16(pf[ks], bv, acc[dt], 0, 0, 0);
        }
      }
    }
  };

  issue(0);
  int cur = 0;
  for (int jt = 0; jt < QT_; ++jt) {
    unsigned short* ksb = &Ks[cur][0];
    _Float16* vtb = &Vt[cur][0];
    *(short8*)&ksb[kr0 * 88 + kc] = krg[0];
    *(short8*)&ksb[(kr0 + 32) * 88 + kc] = krg[1];
#pragma unroll
    for (int i = 0; i < 8; ++i) {
      unsigned lo = (unsigned short)vrg[0][i];   // f16 bits (written f16 at source)
      unsigned hi = (unsigned short)vrg[1][i];
      *(unsigned*)&Vt[cur][(vc * 8 + i) * 72 + 2 * vp] = lo | (hi << 16);
    }
    __syncthreads();
    issue(jt + 1);   // clamped; last iteration's loads are harmless/unused
    if (jt == QT_ - 1) compute(jt, ksb, vtb, TrueT{});
    else               compute(jt, ksb, vtb, FalseT{});
    cur ^= 1;
  }

#pragma unroll
  for (int r = 0; r < 16; ++r) {
    int qw = (r & 3) + 8 * (r >> 2) + 4 * lg2;
    int m = qt * 128 + wave * 32 + qw;
    if (m < N_) {
      float invd = 1.f / dacc[r];
      unsigned short* orow = o2 + (size_t)(b * N_ + m) * C_ + head * HD_ + lq;
      orow[0]  = f2bf(acc[0][r] * invd);
      orow[32] = f2bf(acc[1][r] * invd);
    }
  }
}

extern "C" void kernel_launch(void* const* d_in, const int* in_sizes, int n_in,
                              void* d_out, int out_size, void* d_ws, size_t ws_size,
                              hipStream_t stream) {
  const float* x      = (const float*)d_in[0];
  const float* freqs  = (const float*)d_in[1];
  const float* ln1_g  = (const float*)d_in[2];
  const float* ln1_b  = (const float*)d_in[3];
  const float* qkv_w  = (const float*)d_in[4];
  const float* qkv_b  = (const float*)d_in[5];
  const float* proj_w = (const float*)d_in[6];
  const float* proj_b = (const float*)d_in[7];
  const float* ln2_g  = (const float*)d_in[8];
  const float* ln2_b  = (const float*)d_in[9];
  const float* w1     = (const float*)d_in[10];
  const float* b1     = (const float*)d_in[11];
  const float* w2     = (const float*)d_in[12];
  const float* b2     = (const float*)d_in[13];
  const float* w3     = (const float*)d_in[14];
  const float* b3     = (const float*)d_in[15];
  float* out = (float*)d_out;
  char* ws = (char*)d_ws;

  // workspace layout (bytes) — bf16 weights contiguous for single cvt pass
  unsigned short* hB     = (unsigned short*)(ws + 0);          // [MPAD,768] bf16  16,908,288
  unsigned short* wqkvB  = (unsigned short*)(ws + 16908288);   // [2304,768]        3,538,944
  unsigned short* wprojB = (unsigned short*)(ws + 20447232);   // [768,768]         1,179,648
  unsigned short* w12B   = (unsigned short*)(ws + 21626880);   // [6144,768] Wint   9,437,184
  unsigned short* w3B    = (unsigned short*)(ws + 31064064);   // [768,3072]        4,718,592
  unsigned short* qkvB   = (unsigned short*)(ws + 35782656);   // [MPAD,2304]      50,724,864
  unsigned short* o2B    = (unsigned short*)(ws + 86507520);   // [MPAD,768]       16,908,288
  unsigned short* hidB   = qkvB;  // [MPAD,3072] overlaps dead qkv+o2 after proj

  // fused: all weights -> bf16 (w1/w2 interleaved) + ln1 in one launch
  cvt5_ln_kernel<<<9216 + M_, 256, 0, stream>>>(qkv_w, proj_w, w1, w2, w3, wqkvB,
                                                x, ln1_g, ln1_b, hB);

  // attention branch (rope + q-scale + v-f16 fused into qkv epilogue)
  gemm_bt<0, 1, 128, 1><<<18 * 86, 256, 0, stream>>>(hB, wqkvB, qkvB, qkv_b, nullptr, freqs, 768, 2304, M_, 18);
  attn_kernel<<<B_ * H_ * QT2_, 256, 0, stream>>>(qkvB, o2B);
  gemm_bt<1, 0, 64, 1><<<6 * 172, 256, 0, stream>>>(o2B, wprojB, out, proj_b, x, nullptr, 768, 768, M_, 6);

  // MLP branch (8-phase fused w12 + swiglu -> hid, then w3 + residual)
  ln_kernel<<<M_, 256, 0, stream>>>(out, ln2_g, ln2_b, hB);
  gemm_w12_8p<<<43 * 24, 512, 0, stream>>>(hB, w12B, hidB, b1, b2);
  gemm_bt<3, 0, 128, 1><<<6 * 86, 256, 0, stream>>>(hidB, w3B, out, b3, nullptr, nullptr, 3072, 768, M_, 6);
}

// Round 11
// 523.800 us; speedup vs baseline: 1.1519x; 1.1519x over previous
//
#include <hip/hip_runtime.h>
#include <stdint.h>

#define B_ 8
#define N_ 1374
#define C_ 768
#define H_ 12
#define HD_ 64
#define HID_ 3072
#define M_ (B_*N_)        // 10992
#define MPAD_ 11008       // 86 * 128 = 172 * 64
#define QT_ 22            // ceil(N/64)  (j tiles)
#define QT2_ 11           // ceil(N/128) (q tiles)

// q pre-scale: exp(s/8) == exp2(s * log2(e)/8); fold log2(e)/8 into q at QKV epilogue
#define QSC_ 0.18033688011112042f

typedef __attribute__((ext_vector_type(8))) short short8;
typedef __attribute__((ext_vector_type(4))) float f32x4;
typedef __attribute__((ext_vector_type(16))) float f32x16;
typedef __attribute__((ext_vector_type(4))) _Float16 half4;
typedef __attribute__((ext_vector_type(2))) _Float16 half2v;

__device__ __forceinline__ unsigned short f2bf(float f) {
  unsigned u = __float_as_uint(f);
  u += 0x7FFF + ((u >> 16) & 1);
  return (unsigned short)(u >> 16);
}
__device__ __forceinline__ float bf2f(unsigned short h) {
  return __uint_as_float(((unsigned)h) << 16);
}
__device__ __forceinline__ unsigned short f2h(float f) {
  return __builtin_bit_cast(unsigned short, (_Float16)f);
}

__device__ __forceinline__ half2v pkrtz(float a, float b) {
  return __builtin_bit_cast(half2v, __builtin_amdgcn_cvt_pkrtz(a, b));
}

#if __has_builtin(__builtin_amdgcn_global_load_lds)
#define HAVE_GLL 1
#endif

__device__ __forceinline__ void gld16(const unsigned short* g, unsigned short* l) {
#ifdef HAVE_GLL
  __builtin_amdgcn_global_load_lds((const __attribute__((address_space(1))) void*)g,
                                   (__attribute__((address_space(3))) void*)l, 16, 0, 0);
#else
  *(short8*)l = *(const short8*)g;
#endif
}

// ---------------- LayerNorm body (f32 in, bf16 out), one row per block ----------------
__device__ __forceinline__ void ln_body(const float* __restrict__ in,
    const float* __restrict__ g, const float* __restrict__ bta,
    unsigned short* __restrict__ out, int row, int t) {
  const float* xr = in + (size_t)row * C_;
  float v0 = xr[t], v1 = xr[t + 256], v2 = xr[t + 512];
  float s1 = v0 + v1 + v2;
  float s2 = v0*v0 + v1*v1 + v2*v2;
  for (int off = 1; off < 64; off <<= 1) {
    s1 += __shfl_xor(s1, off, 64);
    s2 += __shfl_xor(s2, off, 64);
  }
  __shared__ float r1[4], r2[4];
  int wave = t >> 6, lane = t & 63;
  if (lane == 0) { r1[wave] = s1; r2[wave] = s2; }
  __syncthreads();
  float tot1 = r1[0] + r1[1] + r1[2] + r1[3];
  float tot2 = r2[0] + r2[1] + r2[2] + r2[3];
  float mu = tot1 * (1.0f / C_);
  float var = tot2 * (1.0f / C_) - mu * mu;
  float rs = rsqrtf(var + 1e-5f);
  size_t ob = (size_t)row * C_;
  out[ob + t]       = f2bf((v0 - mu) * rs * g[t]       + bta[t]);
  out[ob + t + 256] = f2bf((v1 - mu) * rs * g[t + 256] + bta[t + 256]);
  out[ob + t + 512] = f2bf((v2 - mu) * rs * g[t + 512] + bta[t + 512]);
}

__global__ __launch_bounds__(256) void ln_kernel(const float* __restrict__ in,
    const float* __restrict__ g, const float* __restrict__ bta,
    unsigned short* __restrict__ out) {
  ln_body(in, g, bta, out, blockIdx.x, threadIdx.x);
}

// ---------------- fused: weight cvt (blocks 0..9215) + ln1 (blocks 9216..) ----------------
// Independent jobs (cvt reads weights, ln reads x) merged to drop one launch gap.
__global__ __launch_bounds__(256) void cvt5_ln_kernel(
    const float* __restrict__ s0, const float* __restrict__ s1,
    const float* __restrict__ s2, const float* __restrict__ s3,
    const float* __restrict__ s4, unsigned short* __restrict__ out,
    const float* __restrict__ x, const float* __restrict__ ln_g,
    const float* __restrict__ ln_b, unsigned short* __restrict__ h) {
  int blk = blockIdx.x;
  if (blk < 9216) {
    int id = blk * 256 + threadIdx.x;   // float4 index, covers exactly 2359296
    const float* src; int off;
    if (id < 442368)        { src = s0; off = id; }
    else if (id < 589824)   { src = s1; off = id - 442368; }
    else if (id < 1179648)  { src = s2; off = id - 589824; }
    else if (id < 1769472)  { src = s3; off = id - 1179648; }
    else                    { src = s4; off = id - 1769472; }
    float4 v = ((const float4*)src)[off];
    ushort4 o;
    o.x = f2bf(v.x); o.y = f2bf(v.y); o.z = f2bf(v.z); o.w = f2bf(v.w);
    ((ushort4*)out)[id] = o;
  } else {
    ln_body(x, ln_g, ln_b, h, blk - 9216, threadIdx.x);
  }
}

// ---------------- GEMM: out[M,N] = A[M,K](bf16) * W[N,K]^T(bf16) + epilogue ----------------
// Round-4 proven structure: BK=64 via two stride-32 half-K buffers, 2 barriers
// per K-step.  SWZ supergroup swizzle (gemm_bt only; w12's natural 2D order is
// already optimal — r8 measured swizzle there = 4x L2-miss traffic).
// EPI 0: bf16 out + bias0 (+ fused RoPE on q,k windows; q pre-scaled by QSC_;
//        v window written as f16 for the attention PV mfma)
// EPI 1: f32 out = resid + v + bias, row-guarded
// EPI 3: f32 out += v + bias, row-guarded
template<int EPI, int ROPE, int TM, int SWZ>
__global__ __launch_bounds__(256, (TM == 64) ? 4 : 2) void gemm_bt(
    const unsigned short* __restrict__ A,
    const unsigned short* __restrict__ W,
    void* __restrict__ outp,
    const float* __restrict__ bias0,
    const float* __restrict__ resid,
    const float* __restrict__ freqs,
    int K, int ldo, int Mvalid, int X)
{
  constexpr int MI = TM / 32;   // m-subtiles per wave
  __shared__ __align__(16) unsigned short As[2][TM * 32];
  __shared__ __align__(16) unsigned short Bs[2][4096];
  const int t = threadIdx.x;
  const int lane = t & 63;
  const int wave = t >> 6;
  const int wm = (wave >> 1) * (TM / 2);
  const int wn = (wave & 1) * 64;
  const int lr = lane & 15;
  const int lg = lane >> 4;
  const int lk = lg * 8;
  int bx, by;
  if (SWZ) {
    int Y = gridDim.x / X;
    int lin = blockIdx.x;
    int sgsz = X * 8;
    int sg = lin / sgsz;
    int base_y = sg * 8;
    int rows = Y - base_y; if (rows > 8) rows = 8;
    int within = lin - sg * sgsz;
    by = base_y + within % rows;
    bx = within / rows;
  } else {
    bx = blockIdx.x % X;
    by = blockIdx.x / X;
  }
  const int tm0 = by * TM;
  const int tn0 = bx * 128;
  const int r0 = t >> 2;
  const int c0 = (t & 3) * 8;
  const unsigned short* ga0 = A + (size_t)(tm0 + r0) * K + c0;
  const unsigned short* ga1 = A + (size_t)(tm0 + 64 + r0) * K + c0;   // TM==128 only
  const unsigned short* gb0 = W + (size_t)(tn0 + r0) * K + c0;
  const unsigned short* gb1 = W + (size_t)(tn0 + 64 + r0) * K + c0;
  f32x4 zero = {0.f, 0.f, 0.f, 0.f};
  f32x4 acc[MI][4];
#pragma unroll
  for (int mi = 0; mi < MI; ++mi)
#pragma unroll
    for (int ni = 0; ni < 4; ++ni) acc[mi][ni] = zero;

  for (int kt = 0; kt < K; kt += 64) {
    __syncthreads();
    gld16(ga0 + kt,      &As[0][t * 8]);
    gld16(ga0 + kt + 32, &As[1][t * 8]);
    if (TM == 128) {
      gld16(ga1 + kt,      &As[0][2048 + t * 8]);
      gld16(ga1 + kt + 32, &As[1][2048 + t * 8]);
    }
    gld16(gb0 + kt,      &Bs[0][t * 8]);
    gld16(gb1 + kt,      &Bs[0][2048 + t * 8]);
    gld16(gb0 + kt + 32, &Bs[1][t * 8]);
    gld16(gb1 + kt + 32, &Bs[1][2048 + t * 8]);
    __syncthreads();
#pragma unroll
    for (int u = 0; u < 2; ++u) {
      short8 af[MI], bfr[4];
#pragma unroll
      for (int mi = 0; mi < MI; ++mi) af[mi] = *(const short8*)&As[u][(wm + mi * 16 + lr) * 32 + lk];
#pragma unroll
      for (int ni = 0; ni < 4; ++ni) bfr[ni] = *(const short8*)&Bs[u][(wn + ni * 16 + lr) * 32 + lk];
#pragma unroll
      for (int mi = 0; mi < MI; ++mi)
#pragma unroll
        for (int ni = 0; ni < 4; ++ni)
          acc[mi][ni] = __builtin_amdgcn_mfma_f32_16x16x32_bf16(af[mi], bfr[ni], acc[mi][ni], 0, 0, 0);
    }
  }

  if (EPI == 0) {
    // paired epilogue (cols e and e+32 of a 64-aligned window) for fused RoPE
    bool dorope = ROPE && ((tn0 + wn) < 1536);   // q,k windows only; wave-uniform
    bool isq    = ROPE && ((tn0 + wn) < 768);    // q window: fold attn scale into q
    bool isv    = ROPE && ((tn0 + wn) >= 1536);  // v window: write f16 (PV mfma operand)
#pragma unroll
    for (int mi = 0; mi < MI; ++mi) {
#pragma unroll
      for (int p = 0; p < 2; ++p) {
        int col1 = tn0 + wn + p * 16 + lr;
        int col2 = col1 + 32;
        float bv1 = bias0[col1], bv2 = bias0[col2];
        int e = p * 16 + lr;
#pragma unroll
        for (int r = 0; r < 4; ++r) {
          int row = tm0 + wm + mi * 16 + lg * 4 + r;
          float v1 = acc[mi][p][r] + bv1;
          float v2 = acc[mi][p + 2][r] + bv2;
          float o1 = v1, o2 = v2;
          if (dorope) {
            int n = row % N_;
            float f1 = freqs[n * HD_ + e];
            float f2 = freqs[n * HD_ + e + 32];
            float c1, s1, c2, s2;
            __sincosf(f1, &s1, &c1);
            __sincosf(f2, &s2, &c2);
            o1 = v1 * c1 - v2 * s1;
            o2 = v2 * c2 + v1 * s2;
          }
          if (isq) { o1 *= QSC_; o2 *= QSC_; }
          size_t base = (size_t)row * ldo;
          if (isv) {
            ((unsigned short*)outp)[base + col1] = f2h(o1);
            ((unsigned short*)outp)[base + col2] = f2h(o2);
          } else {
            ((unsigned short*)outp)[base + col1] = f2bf(o1);
            ((unsigned short*)outp)[base + col2] = f2bf(o2);
          }
        }
      }
    }
  } else {
#pragma unroll
    for (int mi = 0; mi < MI; ++mi) {
#pragma unroll
      for (int ni = 0; ni < 4; ++ni) {
        int col = tn0 + wn + ni * 16 + lr;
        float bval = bias0[col];
#pragma unroll
        for (int r = 0; r < 4; ++r) {
          int row = tm0 + wm + mi * 16 + lg * 4 + r;
          float v = acc[mi][ni][r] + bval;
          size_t idx = (size_t)row * ldo + col;
          if (EPI == 1) {
            if (row < Mvalid) ((float*)outp)[idx] = resid[idx] + v;
          } else {
            if (row < Mvalid) ((float*)outp)[idx] = ((float*)outp)[idx] + v;
          }
        }
      }
    }
  }
}

// ---------------- Fused GEMM: hid = silu(A*W1^T + b1) * (A*W2^T + b2), BK=64 ----------------
// Round-4 structure, natural 2D grid (x-major order shares the A panel — optimal).
__global__ __launch_bounds__(256, 2) void gemm_w12_swiglu(
    const unsigned short* __restrict__ A,     // [MPAD,768]
    const unsigned short* __restrict__ W1,    // [3072,768]
    const unsigned short* __restrict__ W2,    // [3072,768]
    unsigned short* __restrict__ hid,         // [MPAD,3072]
    const float* __restrict__ b1,
    const float* __restrict__ b2)
{
  __shared__ __align__(16) unsigned short As[2][4096];   // 128x32 per half-K
  __shared__ __align__(16) unsigned short B1s[2][2048];  // 64x32 per half-K
  __shared__ __align__(16) unsigned short B2s[2][2048];
  const int t = threadIdx.x;
  const int lane = t & 63;
  const int wave = t >> 6;
  const int wm = (wave >> 1) * 64;
  const int wn = (wave & 1) * 32;
  const int lr = lane & 15;
  const int lg = lane >> 4;
  const int lk = lg * 8;
  const int tm0 = blockIdx.y * 128;
  const int tn0 = blockIdx.x * 64;
  const int r0 = t >> 2;
  const int c0 = (t & 3) * 8;
  const unsigned short* ga0 = A + (size_t)(tm0 + r0) * 768 + c0;
  const unsigned short* ga1 = A + (size_t)(tm0 + 64 + r0) * 768 + c0;
  const unsigned short* g1 = W1 + (size_t)(tn0 + r0) * 768 + c0;
  const unsigned short* g2 = W2 + (size_t)(tn0 + r0) * 768 + c0;
  f32x4 zero = {0.f, 0.f, 0.f, 0.f};
  f32x4 acc1[4][2], acc2[4][2];
#pragma unroll
  for (int mi = 0; mi < 4; ++mi)
#pragma unroll
    for (int ni = 0; ni < 2; ++ni) { acc1[mi][ni] = zero; acc2[mi][ni] = zero; }

  for (int kt = 0; kt < 768; kt += 64) {
    __syncthreads();
    gld16(ga0 + kt,      &As[0][t * 8]);
    gld16(ga1 + kt,      &As[0][2048 + t * 8]);
    gld16(ga0 + kt + 32, &As[1][t * 8]);
    gld16(ga1 + kt + 32, &As[1][2048 + t * 8]);
    gld16(g1 + kt,       &B1s[0][t * 8]);
    gld16(g1 + kt + 32,  &B1s[1][t * 8]);
    gld16(g2 + kt,       &B2s[0][t * 8]);
    gld16(g2 + kt + 32,  &B2s[1][t * 8]);
    __syncthreads();
#pragma unroll
    for (int u = 0; u < 2; ++u) {
      short8 af[4], b1f[2], b2f[2];
#pragma unroll
      for (int mi = 0; mi < 4; ++mi) af[mi] = *(const short8*)&As[u][(wm + mi * 16 + lr) * 32 + lk];
#pragma unroll
      for (int ni = 0; ni < 2; ++ni) {
        b1f[ni] = *(const short8*)&B1s[u][(wn + ni * 16 + lr) * 32 + lk];
        b2f[ni] = *(const short8*)&B2s[u][(wn + ni * 16 + lr) * 32 + lk];
      }
#pragma unroll
      for (int mi = 0; mi < 4; ++mi)
#pragma unroll
        for (int ni = 0; ni < 2; ++ni) {
          acc1[mi][ni] = __builtin_amdgcn_mfma_f32_16x16x32_bf16(af[mi], b1f[ni], acc1[mi][ni], 0, 0, 0);
          acc2[mi][ni] = __builtin_amdgcn_mfma_f32_16x16x32_bf16(af[mi], b2f[ni], acc2[mi][ni], 0, 0, 0);
        }
    }
  }
#pragma unroll
  for (int mi = 0; mi < 4; ++mi) {
#pragma unroll
    for (int ni = 0; ni < 2; ++ni) {
      int col = tn0 + wn + ni * 16 + lr;
      float bv1 = b1[col], bv2 = b2[col];
#pragma unroll
      for (int r = 0; r < 4; ++r) {
        int row = tm0 + wm + mi * 16 + lg * 4 + r;
        float a1 = acc1[mi][ni][r] + bv1;
        float a2 = acc2[mi][ni][r] + bv2;
        float h = a1 / (1.f + __expf(-a1)) * a2;
        hid[(size_t)row * HID_ + col] = f2bf(h);
      }
    }
  }
}

// ---------------- Attention v5: 32x32 MFMA pipeline (verified) ----------------
struct FalseT { static constexpr bool value = false; };
struct TrueT  { static constexpr bool value = true;  };

__global__ __launch_bounds__(256, 3) void attn_kernel(
    const unsigned short* __restrict__ qkv,   // [MPAD_,2304] roped bf16 q,k; f16 v
    unsigned short* __restrict__ o2)          // [MPAD_,768]  bf16
{
  __shared__ __align__(16) unsigned short Ks[2][64 * 88];  // K rows, stride 88
  __shared__ __align__(16) _Float16 Vt[2][64 * 72];        // V^T [d][j], stride 72
  int bidx = blockIdx.x;
  int qt = bidx % QT2_;
  int bh = bidx / QT2_;
  int head = bh % H_;
  int b = bh / H_;
  int t = threadIdx.x, lane = t & 63, wave = t >> 6;
  int lq = lane & 31, lg2 = lane >> 5;

  short8 bq[4];
  {
    int m = qt * 128 + wave * 32 + lq;
    int mc = (m < N_) ? m : (N_ - 1);
    const unsigned short* qrow = qkv + (size_t)(b * N_ + mc) * 2304 + head * HD_;
#pragma unroll
    for (int c = 0; c < 4; ++c)
      bq[c] = *(const short8*)(qrow + c * 16 + lg2 * 8);
  }

  f32x16 acc[2];   // O[q32][d32] per dt
  f32x16 dacc;     // den[q] (ones-MFMA)
  acc[0] = {}; acc[1] = {}; dacc = {};

  const int kr0 = t >> 3;            // K row unit (0..31), also row+32
  const int kc  = (t & 7) * 8;       // K col (element)
  const int vp  = t & 31;            // j-pair 0..31
  const int vc  = t >> 5;            // d-chunk 0..7
  const unsigned short* kbase = qkv + (size_t)(b * N_) * 2304 + 768  + head * HD_ + kc;
  const unsigned short* vbase = qkv + (size_t)(b * N_) * 2304 + 1536 + head * HD_ + vc * 8;

  short8 krg[2], vrg[2];
  auto issue = [&](int jt) {
    int j0 = jt * 64 + kr0;        if (j0 >= N_) j0 = N_ - 1;
    int j1 = jt * 64 + kr0 + 32;   if (j1 >= N_) j1 = N_ - 1;
    int vj0 = jt * 64 + 2 * vp;    if (vj0 >= N_) vj0 = N_ - 1;
    int vj1 = jt * 64 + 2 * vp + 1; if (vj1 >= N_) vj1 = N_ - 1;
    krg[0] = *(const short8*)(kbase + (size_t)j0 * 2304);
    krg[1] = *(const short8*)(kbase + (size_t)j1 * 2304);
    vrg[0] = *(const short8*)(vbase + (size_t)vj0 * 2304);
    vrg[1] = *(const short8*)(vbase + (size_t)vj1 * 2304);
  };

  const half4 vones = {(_Float16)1.f, (_Float16)1.f, (_Float16)1.f, (_Float16)1.f};

  auto compute = [&](int jt, const unsigned short* ksb, const _Float16* vtb, auto tailc) {
    constexpr bool TAIL = decltype(tailc)::value;
#pragma unroll
    for (int st2 = 0; st2 < 2; ++st2) {
      f32x16 sc = {};
      {
        const unsigned short* krow = &ksb[(st2 * 32 + lq) * 88 + lg2 * 8];
        short8 ak0 = *(const short8*)(krow);
        short8 ak1 = *(const short8*)(krow + 16);
        short8 ak2 = *(const short8*)(krow + 32);
        short8 ak3 = *(const short8*)(krow + 48);
        sc = __builtin_amdgcn_mfma_f32_32x32x16_bf16(ak0, bq[0], sc, 0, 0, 0);
        sc = __builtin_amdgcn_mfma_f32_32x32x16_bf16(ak1, bq[1], sc, 0, 0, 0);
        sc = __builtin_amdgcn_mfma_f32_32x32x16_bf16(ak2, bq[2], sc, 0, 0, 0);
        sc = __builtin_amdgcn_mfma_f32_32x32x16_bf16(ak3, bq[3], sc, 0, 0, 0);
      }
#pragma unroll
      for (int r = 0; r < 16; ++r) {
        float pv = exp2f(sc[r]);
        if (TAIL) {
          int jw = (r & 3) + 8 * (r >> 2) + 4 * lg2;
          int j = jt * 64 + st2 * 32 + jw;
          pv = (j < N_) ? pv : 0.f;
        }
        sc[r] = pv;
      }
      half4 pf[4];
#pragma unroll
      for (int ks = 0; ks < 4; ++ks) {
        union { half4 v; half2v h[2]; } pu;
        pu.h[0] = pkrtz(sc[ks * 4 + 0], sc[ks * 4 + 1]);
        pu.h[1] = pkrtz(sc[ks * 4 + 2], sc[ks * 4 + 3]);
        pf[ks] = pu.v;
      }
#pragma unroll
      for (int ks = 0; ks < 4; ++ks)
        dacc = __builtin_amdgcn_mfma_f32_32x32x8f16(pf[ks], vones, dacc, 0, 0, 0);
#pragma unroll
      for (int dt = 0; dt < 2; ++dt) {
#pragma unroll
        for (int ks = 0; ks < 4; ++ks) {
          half4 bv = *(const half4*)&vtb[(dt * 32 + lq) * 72 + st2 * 32 + ks * 8 + lg2 * 4];
          acc[dt] = __builtin_amdgcn_mfma_f32_32x32x8f16(pf[ks], bv, acc[dt], 0, 0, 0);
        }
      }
    }
  };

  issue(0);
  int cur = 0;
  for (int jt = 0; jt < QT_; ++jt) {
    unsigned short* ksb = &Ks[cur][0];
    _Float16* vtb = &Vt[cur][0];
    *(short8*)&ksb[kr0 * 88 + kc] = krg[0];
    *(short8*)&ksb[(kr0 + 32) * 88 + kc] = krg[1];
#pragma unroll
    for (int i = 0; i < 8; ++i) {
      unsigned lo = (unsigned short)vrg[0][i];   // f16 bits (written f16 at source)
      unsigned hi = (unsigned short)vrg[1][i];
      *(unsigned*)&Vt[cur][(vc * 8 + i) * 72 + 2 * vp] = lo | (hi << 16);
    }
    __syncthreads();
    issue(jt + 1);   // clamped; last iteration's loads are harmless/unused
    if (jt == QT_ - 1) compute(jt, ksb, vtb, TrueT{});
    else               compute(jt, ksb, vtb, FalseT{});
    cur ^= 1;
  }

#pragma unroll
  for (int r = 0; r < 16; ++r) {
    int qw = (r & 3) + 8 * (r >> 2) + 4 * lg2;
    int m = qt * 128 + wave * 32 + qw;
    if (m < N_) {
      float invd = 1.f / dacc[r];
      unsigned short* orow = o2 + (size_t)(b * N_ + m) * C_ + head * HD_ + lq;
      orow[0]  = f2bf(acc[0][r] * invd);
      orow[32] = f2bf(acc[1][r] * invd);
    }
  }
}

extern "C" void kernel_launch(void* const* d_in, const int* in_sizes, int n_in,
                              void* d_out, int out_size, void* d_ws, size_t ws_size,
                              hipStream_t stream) {
  const float* x      = (const float*)d_in[0];
  const float* freqs  = (const float*)d_in[1];
  const float* ln1_g  = (const float*)d_in[2];
  const float* ln1_b  = (const float*)d_in[3];
  const float* qkv_w  = (const float*)d_in[4];
  const float* qkv_b  = (const float*)d_in[5];
  const float* proj_w = (const float*)d_in[6];
  const float* proj_b = (const float*)d_in[7];
  const float* ln2_g  = (const float*)d_in[8];
  const float* ln2_b  = (const float*)d_in[9];
  const float* w1     = (const float*)d_in[10];
  const float* b1     = (const float*)d_in[11];
  const float* w2     = (const float*)d_in[12];
  const float* b2     = (const float*)d_in[13];
  const float* w3     = (const float*)d_in[14];
  const float* b3     = (const float*)d_in[15];
  float* out = (float*)d_out;
  char* ws = (char*)d_ws;

  // workspace layout (bytes) — bf16 weights contiguous for single cvt pass
  unsigned short* hB     = (unsigned short*)(ws + 0);          // [MPAD,768] bf16  16,908,288
  unsigned short* wqkvB  = (unsigned short*)(ws + 16908288);   // [2304,768]        3,538,944
  unsigned short* wprojB = (unsigned short*)(ws + 20447232);   // [768,768]         1,179,648
  unsigned short* w12B   = (unsigned short*)(ws + 21626880);   // [6144,768]        9,437,184
  unsigned short* w3B    = (unsigned short*)(ws + 31064064);   // [768,3072]        4,718,592
  unsigned short* qkvB   = (unsigned short*)(ws + 35782656);   // [MPAD,2304]      50,724,864
  unsigned short* o2B    = (unsigned short*)(ws + 86507520);   // [MPAD,768]       16,908,288
  unsigned short* hidB   = qkvB;  // [MPAD,3072] overlaps dead qkv+o2 after proj

  // fused: all weights -> bf16 + ln1 in one launch (independent jobs)
  cvt5_ln_kernel<<<9216 + M_, 256, 0, stream>>>(qkv_w, proj_w, w1, w2, w3, wqkvB,
                                                x, ln1_g, ln1_b, hB);

  // attention branch (rope + q-scale + v-f16 fused into qkv epilogue)
  gemm_bt<0, 1, 128, 1><<<18 * 86, 256, 0, stream>>>(hB, wqkvB, qkvB, qkv_b, nullptr, freqs, 768, 2304, M_, 18);
  attn_kernel<<<B_ * H_ * QT2_, 256, 0, stream>>>(qkvB, o2B);
  gemm_bt<1, 0, 64, 1><<<6 * 172, 256, 0, stream>>>(o2B, wprojB, out, proj_b, x, nullptr, 768, 768, M_, 6);

  // MLP branch (fused w1|w2 + swiglu -> hid, then w3 + residual)
  ln_kernel<<<M_, 256, 0, stream>>>(out, ln2_g, ln2_b, hB);
  gemm_w12_swiglu<<<dim3(48, 86), 256, 0, stream>>>(hB, w12B, w12B + 3072 * 768, hidB, b1, b2);
  gemm_bt<3, 0, 128, 1><<<6 * 86, 256, 0, stream>>>(hidB, w3B, out, b3, nullptr, nullptr, 3072, 768, M_, 6);
}